// Round 7
// baseline (251.492 us; speedup 1.0000x reference)
//
#include <hip/hip_runtime.h>

#define N_NODES 50000
#define N_EDGES 800000
#define D_FEAT  128
#define NE_ENV  4
#define EPS_F   1e-8f
#define M_CONST 4.0f   // constant softmax shift; exact max cancels in num/denom
#define NB_BUCKET 391  // ceil(50000/128) src-buckets of 128 nodes
#define BINA_EPT 16    // edges per thread in k_binA

typedef __attribute__((ext_vector_type(8))) short bf16x8;
typedef __attribute__((ext_vector_type(4))) float floatx4;
typedef __attribute__((ext_vector_type(2))) float f2v;

static __device__ __forceinline__ unsigned short f2bf(float v) {
    union { float f; unsigned int u; } c; c.f = v;
    unsigned int u = c.u;
    u += 0x7fffu + ((u >> 16) & 1u);   // round-to-nearest-even
    return (unsigned short)(u >> 16);
}

static __device__ __forceinline__ f2v bf2f2(unsigned int v) {
    f2v r;
    r.x = __uint_as_float(v << 16);
    r.y = __uint_as_float(v & 0xffff0000u);
    return r;
}

static __device__ __forceinline__ float lrelu_exp(float z) {
    float lk = z > 0.f ? z : 0.01f * z;
    return __expf(lk - M_CONST);
}

// Fused setup: blocks 0..127 -> b-vectors; 128..383 -> W swizzle; 384..3508 -> degree histogram.
__global__ __launch_bounds__(256) void k_setup(const float* __restrict__ weights, const float* __restrict__ a,
        float* __restrict__ b, unsigned short* __restrict__ wsw,
        const int* __restrict__ row, int* __restrict__ counts) {
    int blk = blockIdx.x;
    if (blk < 128) {
        int wave = threadIdx.x >> 6, lane = threadIdx.x & 63;
        int t = blk * 4 + wave;   // 0..511
        int e = t >> 7, d = t & 127;
        float2 w2 = ((const float2*)(weights + e * 16384 + d * 128))[lane];
        float2 a1 = ((const float2*)(a + e * 256))[lane];
        float2 a2 = ((const float2*)(a + e * 256 + 128))[lane];
        float p1 = w2.x * a1.x + w2.y * a1.y;
        float p2 = w2.x * a2.x + w2.y * a2.y;
#pragma unroll
        for (int off = 32; off > 0; off >>= 1) {
            p1 += __shfl_xor(p1, off, 64);
            p2 += __shfl_xor(p2, off, 64);
        }
        if (lane == 0) {
            b[e * 128 + d] = p1;
            b[512 + e * 128 + d] = p2;
        }
    } else if (blk < 384) {
        // wsw[s*4096 + t*512 + l*8 + j] = Wcat[s*32 + (l>>4)*8 + j][t*16 + (l&15)]
        int idx = (blk - 128) * 256 + threadIdx.x;  // 0..65535
        int j = idx & 7;
        int l = (idx >> 3) & 63;
        int t = (idx >> 9) & 7;
        int s = idx >> 12;
        int k = s * 32 + (l >> 4) * 8 + j;
        int f = t * 16 + (l & 15);
        int e = k >> 7, d = k & 127;
        wsw[idx] = f2bf(weights[e * 16384 + d * 128 + f]);
    } else {
        int k = (blk - 384) * 256 + threadIdx.x;
        if (k < N_EDGES) atomicAdd(&counts[row[k]], 1);
    }
}

// MFMA scores + x->bf16 emit. Block 782 instead runs the 391-bucket scan (counts -> bcur/bbase).
__global__ __launch_bounds__(256) void k_s(const float* __restrict__ x, const float* __restrict__ b,
        float* __restrict__ s_src, float* __restrict__ s_dst, unsigned short* __restrict__ xbf,
        const int* __restrict__ counts, int* __restrict__ bcur, int* __restrict__ bbase) {
    __shared__ int bsum[512];
    if (blockIdx.x == 782) {
        int t = threadIdx.x;
        int o0 = 0, o1 = 0;
        {
            int nb = t << 7;
            int n = min(128, N_NODES - nb);
            for (int j = 0; j < n; ++j) o0 += counts[nb + j];
            bsum[t] = o0;
        }
        {
            int b1 = t + 256;
            if (b1 < NB_BUCKET) {
                int nb = b1 << 7;
                int n = min(128, N_NODES - nb);
                for (int j = 0; j < n; ++j) o1 += counts[nb + j];
            }
            bsum[t + 256] = o1;
        }
        __syncthreads();
        for (int st = 1; st < 512; st <<= 1) {
            int v0 = (t >= st) ? bsum[t - st] : 0;
            int v1 = (t + 256 >= st) ? bsum[t + 256 - st] : 0;
            __syncthreads();
            bsum[t] += v0;
            bsum[t + 256] += v1;
            __syncthreads();
        }
        int e0 = bsum[t] - o0;
        bcur[t] = e0; bbase[t] = e0;
        int b1 = t + 256;
        if (b1 < NB_BUCKET) {
            int e1 = bsum[b1] - o1;
            bcur[b1] = e1; bbase[b1] = e1;
        }
        return;
    }
    int wave = threadIdx.x >> 6, lane = threadIdx.x & 63;
    int gw = blockIdx.x * 4 + wave;
    if (gw >= 3125) return;
    int quad = lane >> 4, lm = lane & 15;
    int base = gw * 16;

    floatx4 acc = (floatx4){0.f, 0.f, 0.f, 0.f};
    const float* xrow = x + (size_t)(base + lm) * 128 + quad * 8;
    unsigned short* xbrow = xbf + (size_t)(base + lm) * 128 + quad * 8;

#pragma unroll
    for (int s = 0; s < 4; ++s) {
        float4 lo = *(const float4*)(xrow + s * 32);
        float4 hi = *(const float4*)(xrow + s * 32 + 4);
        bf16x8 af;
        af[0] = (short)f2bf(lo.x); af[1] = (short)f2bf(lo.y);
        af[2] = (short)f2bf(lo.z); af[3] = (short)f2bf(lo.w);
        af[4] = (short)f2bf(hi.x); af[5] = (short)f2bf(hi.y);
        af[6] = (short)f2bf(hi.z); af[7] = (short)f2bf(hi.w);
        *(bf16x8*)(xbrow + s * 32) = af;

        bf16x8 bfv = (bf16x8){0, 0, 0, 0, 0, 0, 0, 0};
        if (lm < 8) {
            const float* bp = b + lm * 128 + s * 32 + quad * 8;
            float4 b0 = *(const float4*)bp;
            float4 b1 = *(const float4*)(bp + 4);
            bfv[0] = (short)f2bf(b0.x); bfv[1] = (short)f2bf(b0.y);
            bfv[2] = (short)f2bf(b0.z); bfv[3] = (short)f2bf(b0.w);
            bfv[4] = (short)f2bf(b1.x); bfv[5] = (short)f2bf(b1.y);
            bfv[6] = (short)f2bf(b1.z); bfv[7] = (short)f2bf(b1.w);
        }
        acc = __builtin_amdgcn_mfma_f32_16x16x32_bf16(af, bfv, acc, 0, 0, 0);
    }
    if (lm < 8) {
        float* dstp = (lm < 4) ? (s_src + (size_t)(base + quad * 4) * 4 + lm)
                               : (s_dst + (size_t)(base + quad * 4) * 4 + (lm - 4));
#pragma unroll
        for (int r = 0; r < 4; ++r) dstp[r * 4] = acc[r];
    }
}

// Pass A: bin packed edges (s<<16)|d into bucket regions with contiguous per-block bursts.
__global__ __launch_bounds__(256) void k_binA(const int* __restrict__ row, const int* __restrict__ col,
        int* __restrict__ bcur, unsigned int* __restrict__ binned) {
    __shared__ int cnt[NB_BUCKET];
    __shared__ int base[NB_BUCKET];
    int t = threadIdx.x;
    for (int b = t; b < NB_BUCKET; b += 256) cnt[b] = 0;
    __syncthreads();
    unsigned int pk[BINA_EPT];
    int ebase = blockIdx.x * (256 * BINA_EPT) + t;
#pragma unroll
    for (int j = 0; j < BINA_EPT; ++j) {
        int k = ebase + j * 256;
        pk[j] = 0xffffffffu;
        if (k < N_EDGES) {
            unsigned int s = (unsigned int)row[k];
            unsigned int d = (unsigned int)col[k];
            pk[j] = (s << 16) | d;
            atomicAdd(&cnt[s >> 7], 1);
        }
    }
    __syncthreads();
    for (int b = t; b < NB_BUCKET; b += 256) {
        int c = cnt[b];
        base[b] = c ? atomicAdd(&bcur[b], c) : 0;
        cnt[b] = 0;
    }
    __syncthreads();
#pragma unroll
    for (int j = 0; j < BINA_EPT; ++j) {
        if (pk[j] != 0xffffffffu) {
            int b = pk[j] >> 23;
            int off = atomicAdd(&cnt[b], 1);
            binned[base[b] + off] = pk[j];
        }
    }
}

// Pass B: per-bucket finalize. Local 128-node CSR (LDS scan) -> offsets; LDS den accumulation;
// m = ew/(den+EPS); emit pre-scaled c^e = m_e * w^e per edge + cself per node.
__global__ __launch_bounds__(256) void k_binB(const unsigned int* __restrict__ binned,
        const int* __restrict__ counts, const int* __restrict__ bbase,
        const float* __restrict__ s_src, const float* __restrict__ s_dst,
        const float* __restrict__ env_w,
        int* __restrict__ offsets, int* __restrict__ sorted_dst,
        float4* __restrict__ c_sorted, float4* __restrict__ cself) {
    __shared__ int sc[128];
    __shared__ int cur[128];
    __shared__ float denm[128][4];
    int b = blockIdx.x;
    int nb = b << 7;
    int nc = min(128, N_NODES - nb);
    int t = threadIdx.x;
    int myc = 0;
    if (t < nc) myc = counts[nb + t];
    if (t < 128) sc[t] = myc;
    __syncthreads();
    for (int st = 1; st < 128; st <<= 1) {
        int v = 0;
        if (t < 128 && t >= st) v = sc[t - st];
        __syncthreads();
        if (t < 128) sc[t] += v;
        __syncthreads();
    }
    int base = bbase[b];
    float4 wself = {0.f, 0.f, 0.f, 0.f};
    if (t < nc) {
        int excl = base + sc[t] - myc;
        offsets[nb + t] = excl;
        cur[t] = excl;
        float4 sa = *(const float4*)(s_src + (size_t)(nb + t) * 4);
        float4 sb = *(const float4*)(s_dst + (size_t)(nb + t) * 4);
        wself.x = lrelu_exp(sa.x + sb.x);
        wself.y = lrelu_exp(sa.y + sb.y);
        wself.z = lrelu_exp(sa.z + sb.z);
        wself.w = lrelu_exp(sa.w + sb.w);
        denm[t][0] = wself.x; denm[t][1] = wself.y;
        denm[t][2] = wself.z; denm[t][3] = wself.w;
    }
    int tot = sc[127];
    __syncthreads();
    int ebeg = base, eend = base + tot;
    // pass 1: accumulate denominators
    for (int i = ebeg + t; i < eend; i += 256) {
        unsigned int pk = binned[i];
        int s = (int)(pk >> 16), d = (int)(pk & 0xffffu);
        float4 a4 = *(const float4*)(s_src + (size_t)s * 4);
        float4 b4 = *(const float4*)(s_dst + (size_t)d * 4);
        int ls = s - nb;
        atomicAdd(&denm[ls][0], lrelu_exp(a4.x + b4.x));
        atomicAdd(&denm[ls][1], lrelu_exp(a4.y + b4.y));
        atomicAdd(&denm[ls][2], lrelu_exp(a4.z + b4.z));
        atomicAdd(&denm[ls][3], lrelu_exp(a4.w + b4.w));
    }
    __syncthreads();
    if (t < nc) {
        float4 ew = *(const float4*)(env_w + (size_t)(nb + t) * 4);
        float m0 = ew.x / (denm[t][0] + EPS_F);
        float m1 = ew.y / (denm[t][1] + EPS_F);
        float m2 = ew.z / (denm[t][2] + EPS_F);
        float m3 = ew.w / (denm[t][3] + EPS_F);
        denm[t][0] = m0; denm[t][1] = m1; denm[t][2] = m2; denm[t][3] = m3;
        cself[nb + t] = make_float4(m0 * wself.x, m1 * wself.y, m2 * wself.z, m3 * wself.w);
    }
    __syncthreads();
    // pass 2: emit pre-scaled weights + dst, scattered only within this block's own region
    for (int i = ebeg + t; i < eend; i += 256) {
        unsigned int pk = binned[i];
        int s = (int)(pk >> 16), d = (int)(pk & 0xffffu);
        int ls = s - nb;
        float4 a4 = *(const float4*)(s_src + (size_t)s * 4);
        float4 b4 = *(const float4*)(s_dst + (size_t)d * 4);
        float4 c;
        c.x = denm[ls][0] * lrelu_exp(a4.x + b4.x);
        c.y = denm[ls][1] * lrelu_exp(a4.y + b4.y);
        c.z = denm[ls][2] * lrelu_exp(a4.z + b4.z);
        c.w = denm[ls][3] * lrelu_exp(a4.w + b4.w);
        int pos = atomicAdd(&cur[ls], 1);
        sorted_dst[pos] = d;
        c_sorted[pos] = c;
    }
    if (b == NB_BUCKET - 1 && t == 0) offsets[N_NODES] = N_EDGES;
}

// Per-node aggregation with pre-scaled weights: pure gather + 8 (packable) fma per edge.
__global__ __launch_bounds__(256, 8) void k_agg(const unsigned int* __restrict__ xb,
        const int* __restrict__ offsets, const int* __restrict__ sorted_dst,
        const float4* __restrict__ c_sorted, const float4* __restrict__ cself,
        unsigned short* __restrict__ Gp) {
    int wave = threadIdx.x >> 6, lane = threadIdx.x & 63;
    int n = blockIdx.x * 4 + wave;
    if (n >= N_NODES) return;

    f2v a0, a1, a2, a3;
    {
        float4 cs = cself[n];
        f2v xv = bf2f2(xb[(size_t)n * 64 + lane]);
        a0 = cs.x * xv; a1 = cs.y * xv; a2 = cs.z * xv; a3 = cs.w * xv;
    }

    int beg = __builtin_amdgcn_readfirstlane(offsets[n]);
    int end = __builtin_amdgcn_readfirstlane(offsets[n + 1]);
    int i = beg;
    for (; i + 3 < end; i += 4) {
        int d0 = sorted_dst[i],     d1 = sorted_dst[i + 1];
        int d2 = sorted_dst[i + 2], d3 = sorted_dst[i + 3];
        float4 c0 = c_sorted[i],     c1 = c_sorted[i + 1];
        float4 c2 = c_sorted[i + 2], c3 = c_sorted[i + 3];
        unsigned int v0 = xb[(size_t)d0 * 64 + lane];
        unsigned int v1 = xb[(size_t)d1 * 64 + lane];
        unsigned int v2 = xb[(size_t)d2 * 64 + lane];
        unsigned int v3 = xb[(size_t)d3 * 64 + lane];
        f2v x0 = bf2f2(v0), x1 = bf2f2(v1), x2 = bf2f2(v2), x3 = bf2f2(v3);
        a0 += c0.x * x0; a1 += c0.y * x0; a2 += c0.z * x0; a3 += c0.w * x0;
        a0 += c1.x * x1; a1 += c1.y * x1; a2 += c1.z * x1; a3 += c1.w * x1;
        a0 += c2.x * x2; a1 += c2.y * x2; a2 += c2.z * x2; a3 += c2.w * x2;
        a0 += c3.x * x3; a1 += c3.y * x3; a2 += c3.z * x3; a3 += c3.w * x3;
    }
    for (; i < end; ++i) {
        int d0 = sorted_dst[i];
        float4 c0 = c_sorted[i];
        f2v x0 = bf2f2(xb[(size_t)d0 * 64 + lane]);
        a0 += c0.x * x0; a1 += c0.y * x0; a2 += c0.z * x0; a3 += c0.w * x0;
    }

    unsigned int* grow = (unsigned int*)(Gp + (size_t)n * 512);
    grow[0 * 64 + lane] = ((unsigned int)f2bf(a0.y) << 16) | f2bf(a0.x);
    grow[1 * 64 + lane] = ((unsigned int)f2bf(a1.y) << 16) | f2bf(a1.x);
    grow[2 * 64 + lane] = ((unsigned int)f2bf(a2.y) << 16) | f2bf(a2.x);
    grow[3 * 64 + lane] = ((unsigned int)f2bf(a3.y) << 16) | f2bf(a3.x);
}

// out = G'(N x 512, bf16) @ Wcat(512 x 128, bf16 pre-swizzled) + x (residual from bf16 copy).
__global__ __launch_bounds__(256) void k_gemm(const unsigned short* __restrict__ Gp,
        const unsigned short* __restrict__ Wsw,
        const unsigned short* __restrict__ xbf, float* __restrict__ out) {
    int wave = threadIdx.x >> 6, lane = threadIdx.x & 63;
    int gw = blockIdx.x * 4 + wave;
    if (gw >= 3125) return;
    int quad = lane >> 4, lm = lane & 15;
    int m = gw * 16 + lm;

    floatx4 acc[8];
#pragma unroll
    for (int t = 0; t < 8; ++t) acc[t] = (floatx4){0.f, 0.f, 0.f, 0.f};

    const unsigned short* Arow = Gp + (size_t)m * 512 + quad * 8;
#pragma unroll
    for (int s = 0; s < 16; ++s) {
        bf16x8 af = *(const bf16x8*)(Arow + s * 32);
#pragma unroll
        for (int t = 0; t < 8; ++t) {
            bf16x8 bfv = *(const bf16x8*)(Wsw + (((s * 8 + t) * 64 + lane) * 8));
            acc[t] = __builtin_amdgcn_mfma_f32_16x16x32_bf16(af, bfv, acc[t], 0, 0, 0);
        }
    }
    int row_base = gw * 16 + quad * 4;
#pragma unroll
    for (int t = 0; t < 8; ++t) {
        int colc = t * 16 + lm;
#pragma unroll
        for (int r = 0; r < 4; ++r) {
            int rowi = row_base + r;
            float xres = __uint_as_float(((unsigned int)xbf[(size_t)rowi * 128 + colc]) << 16);
            out[(size_t)rowi * 128 + colc] = acc[t][r] + xres;
        }
    }
}

extern "C" void kernel_launch(void* const* d_in, const int* in_sizes, int n_in,
                              void* d_out, int out_size, void* d_ws, size_t ws_size,
                              hipStream_t stream) {
    const float* x       = (const float*)d_in[0];
    const int*   adj     = (const int*)d_in[1];
    const int*   row     = adj;
    const int*   col     = adj + N_EDGES;
    const float* env_w   = (const float*)d_in[2];
    const float* weights = (const float*)d_in[3];
    const float* a       = (const float*)d_in[4];
    float* out = (float*)d_out;

    char* ws = (char*)d_ws;
    size_t off = 0;
    auto alloc = [&](size_t bytes) -> char* {
        char* p = ws + off;
        off += (bytes + 255) & ~(size_t)255;
        return p;
    };
    float* b          = (float*)alloc(1024 * 4);
    float* s_src      = (float*)alloc((size_t)N_NODES * 4 * 4);
    float* s_dst      = (float*)alloc((size_t)N_NODES * 4 * 4);
    int*   counts     = (int*)alloc((size_t)N_NODES * 4);
    int*   offsets    = (int*)alloc((size_t)(N_NODES + 1) * 4);
    int*   bcur       = (int*)alloc(512 * 4);
    int*   bbase      = (int*)alloc(512 * 4);
    unsigned int* binned = (unsigned int*)alloc((size_t)N_EDGES * 4);
    int*   sorted_dst = (int*)alloc((size_t)N_EDGES * 4);
    float4* c_sorted  = (float4*)alloc((size_t)N_EDGES * 16);
    float4* cself     = (float4*)alloc((size_t)N_NODES * 16);
    unsigned short* wsw = (unsigned short*)alloc(65536 * 2);
    unsigned short* xbf = (unsigned short*)alloc((size_t)N_NODES * 128 * 2);
    unsigned short* Gp  = (unsigned short*)alloc((size_t)N_NODES * 512 * 2);

    hipMemsetAsync(counts, 0, (size_t)N_NODES * 4, stream);
    k_setup<<<3509, 256, 0, stream>>>(weights, a, b, wsw, row, counts);
    k_s<<<783, 256, 0, stream>>>(x, b, s_src, s_dst, xbf, counts, bcur, bbase);
    k_binA<<<196, 256, 0, stream>>>(row, col, bcur, binned);
    k_binB<<<NB_BUCKET, 256, 0, stream>>>(binned, counts, bbase, s_src, s_dst, env_w,
                                          offsets, sorted_dst, c_sorted, cself);
    k_agg<<<12500, 256, 0, stream>>>((const unsigned int*)xbf, offsets, sorted_dst, c_sorted, cself, Gp);
    k_gemm<<<782, 256, 0, stream>>>(Gp, wsw, xbf, out);
}